// Round 5
// baseline (269.510 us; speedup 1.0000x reference)
//
#include <hip/hip_runtime.h>
#include <hip/hip_fp16.h>

// GRU (reset_after, inference) fused with dense head.
// B=1024 rows, T=512 steps, F=16 features, H=64 hidden. ONE WAVE PER ROW.
// Round-5 changes on top of the dot2 structure:
//  1) amdgpu_waves_per_eu(1,1): rounds 1-4 all showed VGPR_Count ~124-144 =
//     the allocator targeting 4 waves/EU (512/4=128) and parking ~120 weight
//     regs in AGPRs (v_accvgpr_read per use = ~240 cy/step bloat; VALUBusy
//     63% of a 1008-cy step vs ~300 cy of real work). Grid = 1024 waves on
//     1024 SIMDs -> occupancy >1 wave/SIMD is unreachable; give the
//     allocator the full register budget.
//  2) x fragments preloaded one step ahead (xpA/xpB, unroll x2, all static
//     indices): the 24 x-dot2s fill the h publish->broadcast LDS bubble.
//  3) accumulator chains split in two (16-deep instead of 32-deep).

#define T_ 512
#define F_ 16
#define H_ 64

typedef _Float16 half_t;
typedef _Float16 h2 __attribute__((ext_vector_type(2)));
typedef _Float16 h4 __attribute__((ext_vector_type(4)));
typedef _Float16 h8 __attribute__((ext_vector_type(8)));

__device__ __forceinline__ float fdot2f(h2 a, h2 b, float c) {
#if __has_builtin(__builtin_amdgcn_fdot2)
    return __builtin_amdgcn_fdot2(a, b, c, false);   // v_dot2_f32_f16
#else
    return fmaf((float)a.x, (float)b.x, fmaf((float)a.y, (float)b.y, c));
#endif
}

__device__ __forceinline__ float fast_rcp(float a) {
    return __builtin_amdgcn_rcpf(a);   // v_rcp_f32, ~1 ULP
}
__device__ __forceinline__ float sigm(float a) {
    return fast_rcp(1.0f + __expf(-a));
}
__device__ __forceinline__ float tanh_fast(float a) {
    // tanh(a) = 1 - 2/(exp(2a)+1); saturates correctly for large |a|
    return 1.0f - 2.0f * fast_rcp(__expf(2.0f * a) + 1.0f);
}

__global__ __launch_bounds__(64)
__attribute__((amdgpu_waves_per_eu(1, 1)))
void gru_fused(
    const float* __restrict__ x, const float* __restrict__ W,
    const float* __restrict__ U, const float* __restrict__ b,
    const float* __restrict__ w1, const float* __restrict__ b1,
    const float* __restrict__ gamma_, const float* __restrict__ beta_,
    const float* __restrict__ mmean, const float* __restrict__ mvar,
    const float* __restrict__ w2, const float* __restrict__ b2,
    float* __restrict__ out)
{
    // +2 steps of slack so the pipelined x-preload for t+2 never reads OOB
    __shared__ __align__(16) half_t xs16[(T_ + 2) * F_];  // ~16.4 KB
    __shared__ __align__(16) half_t hb16[H_];             // 128 B: h bcast

    const int j   = threadIdx.x;             // hidden unit, 0..63
    const int row = blockIdx.x;

    // ---- stage x[row] into LDS as packed fp16 (32 iters) ----
    const float4* xr4 = (const float4*)(x + (size_t)row * (T_ * F_));
    #pragma unroll
    for (int i = 0; i < (T_ * F_ / 4) / 64; ++i) {   // 32 iters
        const float4 v = xr4[i * 64 + j];
        h4 p = { (half_t)v.x, (half_t)v.y, (half_t)v.z, (half_t)v.w };
        ((h4*)xs16)[i * 64 + j] = p;                 // ds_write_b64
    }
    hb16[j] = (half_t)0.0f;                          // h0 = 0
    { // zero the 2-step slack region (never used numerically, keep defined)
        if (j < 32) ((half_t*)xs16)[T_ * F_ + j] = (half_t)0.0f;
    }

    // ---- weights packed along k as half2 (120 VGPRs) ----
    h2 uz2[32], ur2[32], uh2[32];
    #pragma unroll
    for (int m = 0; m < 32; ++m) {
        uz2[m] = h2{ (half_t)U[(2*m)*192 +       j], (half_t)U[(2*m+1)*192 +       j] };
        ur2[m] = h2{ (half_t)U[(2*m)*192 +  64 + j], (half_t)U[(2*m+1)*192 +  64 + j] };
        uh2[m] = h2{ (half_t)U[(2*m)*192 + 128 + j], (half_t)U[(2*m+1)*192 + 128 + j] };
    }
    h2 wz2[8], wr2[8], wh2[8];
    #pragma unroll
    for (int p = 0; p < 8; ++p) {
        wz2[p] = h2{ (half_t)W[(2*p)*192 +       j], (half_t)W[(2*p+1)*192 +       j] };
        wr2[p] = h2{ (half_t)W[(2*p)*192 +  64 + j], (half_t)W[(2*p+1)*192 +  64 + j] };
        wh2[p] = h2{ (half_t)W[(2*p)*192 + 128 + j], (half_t)W[(2*p+1)*192 + 128 + j] };
    }
    // biases (b is [2,192]: b[0]=input bias, b[1]=recurrent bias)
    const float bz  = b[j]       + b[192 + j];   // bi_z + br_z
    const float brr = b[64 + j]  + b[256 + j];   // bi_r + br_r
    const float bxh = b[128 + j];                // bi_h (x-part)
    const float brh = b[320 + j];                // br_h (rec-part)

    __syncthreads();   // LDS visible (single wave: folds to a waitcnt)

    float h = 0.0f;

    // One GRU step. XPU: preloaded x fragments for this step (consumed
    // while the hp broadcast reads are in flight -> fills the LDS bubble).
    // XPL: buffer to preload x for step TLOAD (static token -> registers).
#define STEP(XPU, XPL, TLOAD) do {                                        \
    h2 hp[32];                                                            \
    _Pragma("unroll")                                                     \
    for (int q = 0; q < 8; ++q)                                           \
        *((h8*)&hp[4 * q]) = ((const h8*)hb16)[q];      /* ds_read_b128 */\
    float az0 = bz, ar0 = brr, axh0 = bxh;                                \
    _Pragma("unroll")                                                     \
    for (int p = 0; p < 8; ++p) {      /* x-part: independent of hp */    \
        az0  = fdot2f(XPU[p], wz2[p], az0);                               \
        ar0  = fdot2f(XPU[p], wr2[p], ar0);                               \
        axh0 = fdot2f(XPU[p], wh2[p], axh0);                              \
    }                                                                     \
    _Pragma("unroll")                                                     \
    for (int q = 0; q < 2; ++q)        /* preload x for step TLOAD */     \
        *((h8*)&XPL[4 * q]) = ((const h8*)xs16)[(TLOAD) * 2 + q];         \
    float az1 = 0.f, ar1 = 0.f, arh0 = brh, arh1 = 0.f;                   \
    _Pragma("unroll")                                                     \
    for (int m = 0; m < 32; m += 2) {  /* recurrence: 96 dot2, 6 chains */\
        az0  = fdot2f(hp[m],     uz2[m],     az0);                        \
        ar0  = fdot2f(hp[m],     ur2[m],     ar0);                        \
        arh0 = fdot2f(hp[m],     uh2[m],     arh0);                       \
        az1  = fdot2f(hp[m + 1], uz2[m + 1], az1);                        \
        ar1  = fdot2f(hp[m + 1], ur2[m + 1], ar1);                        \
        arh1 = fdot2f(hp[m + 1], uh2[m + 1], arh1);                       \
    }                                                                     \
    const float z  = sigm(az0 + az1);                                     \
    const float r  = sigm(ar0 + ar1);                                     \
    const float hh = tanh_fast(fmaf(r, arh0 + arh1, axh0));               \
    h = fmaf(z, h - hh, hh);                                              \
    hb16[j] = (half_t)h;                                /* ds_write_b16 */\
} while (0)

    h2 xpA[8], xpB[8];
    #pragma unroll
    for (int q = 0; q < 2; ++q)
        *((h8*)&xpA[4 * q]) = ((const h8*)xs16)[q];     // x_0

    for (int t = 0; t < T_; t += 2) {
        STEP(xpA, xpB, t + 1);
        STEP(xpB, xpA, t + 2);   // t+2 == T_ on last iter: reads slack, unused
    }
#undef STEP

    // ---- head: y = relu(h @ w1 + b1); BN(inference); out = y @ w2 + b2 ----
    float y = b1[j];
    const int hb2 = __float_as_int(h);
    #pragma unroll
    for (int k = 0; k < H_; ++k) {
        const float hk = __int_as_float(__builtin_amdgcn_readlane(hb2, k));
        y = fmaf(hk, w1[k * H_ + j], y);
    }
    y = fmaxf(y, 0.0f);
    y = fmaf((y - mmean[j]) * rsqrtf(mvar[j] + 1e-3f), gamma_[j], beta_[j]);

    float acc = y * w2[j];
    #pragma unroll
    for (int off = 32; off > 0; off >>= 1)
        acc += __shfl_down(acc, off, 64);
    if (j == 0) out[row] = acc + b2[0];
}

extern "C" void kernel_launch(void* const* d_in, const int* in_sizes, int n_in,
                              void* d_out, int out_size, void* d_ws, size_t ws_size,
                              hipStream_t stream) {
    const float* x      = (const float*)d_in[0];
    const float* W      = (const float*)d_in[1];
    const float* U      = (const float*)d_in[2];
    const float* b      = (const float*)d_in[3];
    const float* w1     = (const float*)d_in[4];
    const float* b1     = (const float*)d_in[5];
    const float* gamma_ = (const float*)d_in[6];
    const float* beta_  = (const float*)d_in[7];
    const float* mmean  = (const float*)d_in[8];
    const float* mvar   = (const float*)d_in[9];
    const float* w2     = (const float*)d_in[10];
    const float* b2     = (const float*)d_in[11];
    float* out = (float*)d_out;

    const int B = in_sizes[0] / (T_ * F_);   // 1024
    gru_fused<<<B, 64, 0, stream>>>(x, W, U, b, w1, b1, gamma_, beta_,
                                    mmean, mvar, w2, b2, out);
}